// Round 1
// baseline (6736.520 us; speedup 1.0000x reference)
//
#include <hip/hip_runtime.h>
#include <math.h>

// Problem constants
#define BB 32
#define CC 512
#define SS 256      // kv tokens
#define DD 2048     // d_model
#define DIN 512
#define NH 8
#define DHD 64
#define TT 50
#define MM 25
#define HHID 16
#define NSA 512
#define NSO 512
#define NOUT 1000

// ---------------------------------------------------------------------------
// Init: decays, sync states, act0, trace0
// ---------------------------------------------------------------------------
__global__ void init_kernel(const float* __restrict__ dec_a, const float* __restrict__ dec_o,
                            const float* __restrict__ start_act, const float* __restrict__ start_trace,
                            const int* __restrict__ idx_lo, const int* __restrict__ idx_ro,
                            float* __restrict__ r_a, float* __restrict__ r_o,
                            float* __restrict__ a_a, float* __restrict__ b_a,
                            float* __restrict__ a_o, float* __restrict__ b_o,
                            float* __restrict__ act, float* __restrict__ trace)
{
    int i = blockIdx.x * 256 + threadIdx.x;
    if (i < 512) {
        r_a[i] = expf(-fminf(fmaxf(dec_a[i], 0.f), 15.f));
        r_o[i] = expf(-fminf(fmaxf(dec_o[i], 0.f), 15.f));
    }
    if (i < BB * NSA) {
        a_a[i] = 0.f; b_a[i] = 0.f;
        int j = i & 511;
        a_o[i] = start_act[idx_lo[j]] * start_act[idx_ro[j]];
        b_o[i] = 1.f;
    }
    if (i < BB * DD) act[i] = start_act[i & (DD - 1)];
    if (i < BB * MM * DD) {
        int rem = i % (MM * DD);
        int m = rem / DD, d = rem % DD;
        trace[i] = start_trace[d * MM + m];   // start_trace is (D,M)
    }
}

// ---------------------------------------------------------------------------
// Generic 64x64 tiled GEMM. AMODE 0: row-major A[row*K+k]. AMODE 1: A is x
// (B,C,S) with row=(b,s), k=c. SMODE 0: plain row-major + bias. SMODE 1:
// store khT (B,H,DH,S). SMODE 2: store vh (B,H,S,DH).
// ---------------------------------------------------------------------------
template<int AMODE, int SMODE>
__global__ void gemm64(const float* __restrict__ A, const float* __restrict__ Bm,
                       const float* __restrict__ bias, float* __restrict__ Cm,
                       int Mdim, int Ndim, int Kdim)
{
    __shared__ float As[16 * 65];
    __shared__ float Bs[16 * 64];
    int row0 = blockIdx.x * 64;
    int col0 = blockIdx.y * 64;
    int t = threadIdx.x;
    int tx = t & 15, ty = t >> 4;
    float acc[4][4] = {};
    for (int k0 = 0; k0 < Kdim; k0 += 16) {
        if (AMODE == 0) {
            for (int i = t; i < 1024; i += 256) {
                int kk = i & 15, r = i >> 4;
                As[kk * 65 + r] = A[(size_t)(row0 + r) * Kdim + k0 + kk];
            }
        } else {
            int b = row0 / SS, s0 = row0 % SS;
            for (int i = t; i < 1024; i += 256) {
                int r = i & 63, kk = i >> 6;
                As[kk * 65 + r] = A[((size_t)b * CC + k0 + kk) * SS + s0 + r];
            }
        }
        for (int i = t; i < 1024; i += 256) {
            int c = i & 63, kk = i >> 6;
            Bs[kk * 64 + c] = Bm[(size_t)(k0 + kk) * Ndim + col0 + c];
        }
        __syncthreads();
        #pragma unroll
        for (int kk = 0; kk < 16; ++kk) {
            float a[4], bb[4];
            #pragma unroll
            for (int i = 0; i < 4; i++) a[i] = As[kk * 65 + ty * 4 + i];
            #pragma unroll
            for (int j = 0; j < 4; j++) bb[j] = Bs[kk * 64 + tx * 4 + j];
            #pragma unroll
            for (int i = 0; i < 4; i++)
                #pragma unroll
                for (int j = 0; j < 4; j++) acc[i][j] += a[i] * bb[j];
        }
        __syncthreads();
    }
    #pragma unroll
    for (int i = 0; i < 4; i++)
        #pragma unroll
        for (int j = 0; j < 4; j++) {
            int row = row0 + ty * 4 + i, col = col0 + tx * 4 + j;
            float v = acc[i][j] + (bias ? bias[col] : 0.f);
            if (SMODE == 0) {
                Cm[(size_t)row * Ndim + col] = v;
            } else if (SMODE == 1) {
                int b = row / SS, s = row % SS, h = col >> 6, dh = col & 63;
                Cm[(((size_t)b * NH + h) * DHD + dh) * SS + s] = v;
            } else {
                int b = row / SS, s = row % SS, h = col >> 6, dh = col & 63;
                Cm[(((size_t)b * NH + h) * SS + s) * DHD + dh] = v;
            }
        }
}

// LayerNorm over rows of 512 (in place), g/b applied
__global__ void ln_rows(float* __restrict__ buf, const float* __restrict__ g,
                        const float* __restrict__ bta)
{
    int row = blockIdx.x, t = threadIdx.x;
    __shared__ float red[256];
    float v0 = buf[(size_t)row * 512 + t];
    float v1 = buf[(size_t)row * 512 + 256 + t];
    red[t] = v0 + v1; __syncthreads();
    for (int off = 128; off; off >>= 1) { if (t < off) red[t] += red[t + off]; __syncthreads(); }
    float mu = red[0] * (1.f / 512.f); __syncthreads();
    float d0 = v0 - mu, d1 = v1 - mu;
    red[t] = d0 * d0 + d1 * d1; __syncthreads();
    for (int off = 128; off; off >>= 1) { if (t < off) red[t] += red[t + off]; __syncthreads(); }
    float rstd = 1.f / sqrtf(red[0] * (1.f / 512.f) + 1e-5f);
    buf[(size_t)row * 512 + t]       = d0 * rstd * g[t] + bta[t];
    buf[(size_t)row * 512 + 256 + t] = d1 * rstd * g[t + 256] + bta[t + 256];
}

// bqq = q_b @ Wq + bq
__global__ void bqq_kernel(const float* __restrict__ q_b, const float* __restrict__ Wq,
                           const float* __restrict__ bq, float* __restrict__ bqq)
{
    int c = blockIdx.x * 256 + threadIdx.x;
    if (c >= 512) return;
    float acc = bq[c];
    for (int k = 0; k < 512; k++) acc += q_b[k] * Wq[k * 512 + c];
    bqq[c] = acc;
}

// bias2 = bo @ syn_w[0:512,:] + syn_b
__global__ void bias2_kernel(const float* __restrict__ bo, const float* __restrict__ syn_w,
                             const float* __restrict__ syn_b, float* __restrict__ bias2)
{
    int c = blockIdx.x * 256 + threadIdx.x;
    if (c >= 4096) return;
    float acc = syn_b[c];
    for (int k = 0; k < 512; k++) acc += bo[k] * syn_w[(size_t)k * 4096 + c];
    bias2[c] = acc;
}

// ---------------------------------------------------------------------------
// Per-tick kernels
// ---------------------------------------------------------------------------
__global__ void sync_a_kernel(const float* __restrict__ act, const int* __restrict__ la,
                              const int* __restrict__ ra, const float* __restrict__ r_a,
                              float* __restrict__ a_a, float* __restrict__ b_a,
                              float* __restrict__ sync_a)
{
    int i = blockIdx.x * 256 + threadIdx.x;   // 16384
    int b = i >> 9, j = i & 511;
    float p = act[b * DD + la[j]] * act[b * DD + ra[j]];
    float aa = r_a[j] * a_a[i] + p; a_a[i] = aa;
    float bb = r_a[j] * b_a[i] + 1.f; b_a[i] = bb;
    sync_a[i] = aa / sqrtf(bb);
}

// qh = sync_a @ Wqq + bqq   (Wqq = q_w@Wq precomputed)
__global__ void qh_kernel(const float* __restrict__ sync_a, const float* __restrict__ Wqq,
                          const float* __restrict__ bqq, float* __restrict__ qh)
{
    int i = blockIdx.x * 256 + threadIdx.x;   // 16384
    int b = i >> 9, c = i & 511;
    const float* srow = sync_a + b * 512;
    float acc = bqq[c];
    #pragma unroll 8
    for (int k = 0; k < 512; k++) acc += srow[k] * Wqq[k * 512 + c];
    qh[i] = acc;
}

// one block per (b,h): scores -> softmax -> weighted V
__global__ void attn_kernel(const float* __restrict__ qh, const float* __restrict__ khT,
                            const float* __restrict__ vh, float* __restrict__ obuf)
{
    int bh = blockIdx.x;
    int b = bh >> 3, h = bh & 7;
    int t = threadIdx.x;
    __shared__ float qs[64];
    __shared__ float ps[256];
    __shared__ float red[256];
    if (t < 64) qs[t] = qh[b * 512 + h * 64 + t];
    __syncthreads();
    const float* kb = khT + (size_t)bh * 64 * 256;   // [dh][s]
    float sc = 0.f;
    #pragma unroll 8
    for (int dh = 0; dh < 64; ++dh) sc += qs[dh] * kb[dh * 256 + t];
    sc *= 0.125f;
    red[t] = sc; __syncthreads();
    for (int off = 128; off; off >>= 1) { if (t < off) red[t] = fmaxf(red[t], red[t + off]); __syncthreads(); }
    float mx = red[0]; __syncthreads();
    float e = expf(sc - mx);
    red[t] = e; __syncthreads();
    for (int off = 128; off; off >>= 1) { if (t < off) red[t] += red[t + off]; __syncthreads(); }
    float inv = 1.f / red[0];
    ps[t] = e * inv;
    __syncthreads();
    int dh = t & 63, ch = t >> 6;
    const float* vb = vh + (size_t)bh * 256 * 64;    // [s][dh]
    float acc = 0.f;
    for (int s = ch * 64; s < ch * 64 + 64; ++s) acc += ps[s] * vb[s * 64 + dh];
    red[t] = acc; __syncthreads();
    if (t < 128) red[t] += red[t + 128];
    __syncthreads();
    if (t < 64) obuf[b * 512 + h * 64 + t] = red[t] + red[t + 64];
}

// u = o@W2 + act@syn_w[512:,:] (+bias2 added later); K-split partials.
// grid (32 n-tiles of 128, 16 k-splits of 160), block 256
__global__ void syn_gemm(const float* __restrict__ obuf, const float* __restrict__ act,
                         const float* __restrict__ W2, const float* __restrict__ syn_w,
                         float* __restrict__ upart)
{
    __shared__ float As[32 * 161];
    int n0 = blockIdx.x * 128;
    int ks = blockIdx.y;
    int k0 = ks * 160;
    int t = threadIdx.x;
    for (int i = t; i < 32 * 160; i += 256) {
        int k = i % 160, r = i / 160;
        int kk = k0 + k;
        float v = (kk < 512) ? obuf[r * 512 + kk] : act[r * 2048 + (kk - 512)];
        As[r * 161 + k] = v;
    }
    __syncthreads();
    int ct = t & 31, rt = t >> 5;
    int c0 = n0 + ct * 4;
    int rt4 = rt * 4;
    float acc[4][4] = {};
    #pragma unroll 2
    for (int k = 0; k < 160; ++k) {
        int kk = k0 + k;
        const float* wr = (kk < 512 ? W2 : syn_w) + (size_t)kk * 4096 + c0;
        float4 w4 = *(const float4*)wr;
        float a0 = As[(rt4 + 0) * 161 + k];
        float a1 = As[(rt4 + 1) * 161 + k];
        float a2 = As[(rt4 + 2) * 161 + k];
        float a3 = As[(rt4 + 3) * 161 + k];
        acc[0][0] += a0 * w4.x; acc[0][1] += a0 * w4.y; acc[0][2] += a0 * w4.z; acc[0][3] += a0 * w4.w;
        acc[1][0] += a1 * w4.x; acc[1][1] += a1 * w4.y; acc[1][2] += a1 * w4.z; acc[1][3] += a1 * w4.w;
        acc[2][0] += a2 * w4.x; acc[2][1] += a2 * w4.y; acc[2][2] += a2 * w4.z; acc[2][3] += a2 * w4.w;
        acc[3][0] += a3 * w4.x; acc[3][1] += a3 * w4.y; acc[3][2] += a3 * w4.z; acc[3][3] += a3 * w4.w;
    }
    #pragma unroll
    for (int i = 0; i < 4; i++) {
        float4 v = make_float4(acc[i][0], acc[i][1], acc[i][2], acc[i][3]);
        *(float4*)(upart + ((size_t)(ks * 32) + rt4 + i) * 4096 + c0) = v;
    }
}

// sum k-split partials, add bias2, GLU, LayerNorm, write into trace slot t%25
__global__ void glu_ln_kernel(const float* __restrict__ upart, const float* __restrict__ bias2,
                              const float* __restrict__ g, const float* __restrict__ bta,
                              float* __restrict__ trace, int t_iter)
{
    int b = blockIdx.x, t = threadIdx.x;
    __shared__ float red[256];
    float vals[8];
    float loc = 0.f;
    #pragma unroll
    for (int ii = 0; ii < 8; ++ii) {
        int d = t + ii * 256;
        float a = bias2[d], bb = bias2[d + 2048];
        for (int ks = 0; ks < 16; ++ks) {
            const float* rowp = upart + (size_t)(ks * 32 + b) * 4096;
            a += rowp[d];
            bb += rowp[d + 2048];
        }
        float gl = a * (1.f / (1.f + expf(-bb)));
        vals[ii] = gl; loc += gl;
    }
    red[t] = loc; __syncthreads();
    for (int off = 128; off; off >>= 1) { if (t < off) red[t] += red[t + off]; __syncthreads(); }
    float mu = red[0] * (1.f / 2048.f); __syncthreads();
    float l2 = 0.f;
    #pragma unroll
    for (int ii = 0; ii < 8; ++ii) { float dq = vals[ii] - mu; l2 += dq * dq; }
    red[t] = l2; __syncthreads();
    for (int off = 128; off; off >>= 1) { if (t < off) red[t] += red[t + off]; __syncthreads(); }
    float rstd = 1.f / sqrtf(red[0] * (1.f / 2048.f) + 1e-5f);
    float* trow = trace + ((size_t)b * MM + (t_iter % MM)) * DD;
    #pragma unroll
    for (int ii = 0; ii < 8; ++ii) {
        int d = t + ii * 256;
        trow[d] = (vals[ii] - mu) * rstd * g[d] + bta[d];
    }
}

// per-neuron MLP: thread per (b,d)
__global__ void nlm_kernel(const float* __restrict__ trace, const float* __restrict__ w1,
                           const float* __restrict__ b1, const float* __restrict__ w2,
                           const float* __restrict__ b2, float* __restrict__ act, int t_iter)
{
    int i = blockIdx.x * 256 + threadIdx.x;
    int b = i >> 11, d = i & 2047;
    float hp[32];
    #pragma unroll
    for (int h = 0; h < 32; h++) hp[h] = b1[d * 32 + h];
    const float* tr = trace + (size_t)b * MM * DD;
    for (int m = 0; m < 25; m++) {
        int mph = (t_iter + 1 + m) % 25;      // logical->physical circular map
        float tv = tr[mph * DD + d];
        #pragma unroll
        for (int h = 0; h < 32; h++) hp[h] += tv * w1[((size_t)m * 32 + h) * DD + d];
    }
    float o0 = b2[d * 2], o1 = b2[d * 2 + 1];
    #pragma unroll
    for (int h = 0; h < 16; h++) {
        float hv = hp[h] * (1.f / (1.f + expf(-hp[h + 16])));
        o0 += hv * w2[((size_t)h * 2) * DD + d];
        o1 += hv * w2[((size_t)h * 2 + 1) * DD + d];
    }
    act[i] = o0 * (1.f / (1.f + expf(-o1)));
}

__global__ void sync_o_kernel(const float* __restrict__ act, const int* __restrict__ lo,
                              const int* __restrict__ ro, const float* __restrict__ r_o,
                              float* __restrict__ a_o, float* __restrict__ b_o,
                              float* __restrict__ sync_o, float* __restrict__ out_sync, int t_iter)
{
    int i = blockIdx.x * 256 + threadIdx.x;
    int b = i >> 9, j = i & 511;
    float p = act[b * DD + lo[j]] * act[b * DD + ro[j]];
    float aa = r_o[j] * a_o[i] + p; a_o[i] = aa;
    float bb = r_o[j] * b_o[i] + 1.f; b_o[i] = bb;
    float s = aa / sqrtf(bb);
    sync_o[i] = s;
    if (t_iter == TT - 1) out_sync[i] = s;
}

// pred partials: grid (8 c-tiles of 128, 8 k-splits of 64), block 256
__global__ void pred_gemm(const float* __restrict__ sync_o, const float* __restrict__ out_w,
                          float* __restrict__ ppart)
{
    __shared__ float As[32 * 65];
    int c0 = blockIdx.x * 128;
    int ks = blockIdx.y, k0 = ks * 64;
    int t = threadIdx.x;
    for (int i = t; i < 32 * 64; i += 256) {
        int k = i & 63, r = i >> 6;
        As[r * 65 + k] = sync_o[r * 512 + k0 + k];
    }
    __syncthreads();
    int ct = t & 31, rt = t >> 5;
    int cc = c0 + ct * 4;
    int rt4 = rt * 4;
    if (cc < 1000) {
        float acc[4][4] = {};
        #pragma unroll 4
        for (int k = 0; k < 64; ++k) {
            const float* wr = out_w + (size_t)(k0 + k) * 1000 + cc;
            float w0 = wr[0], w1 = wr[1], w2 = wr[2], w3 = wr[3];
            float a0 = As[(rt4 + 0) * 65 + k];
            float a1 = As[(rt4 + 1) * 65 + k];
            float a2 = As[(rt4 + 2) * 65 + k];
            float a3 = As[(rt4 + 3) * 65 + k];
            acc[0][0] += a0 * w0; acc[0][1] += a0 * w1; acc[0][2] += a0 * w2; acc[0][3] += a0 * w3;
            acc[1][0] += a1 * w0; acc[1][1] += a1 * w1; acc[1][2] += a1 * w2; acc[1][3] += a1 * w3;
            acc[2][0] += a2 * w0; acc[2][1] += a2 * w1; acc[2][2] += a2 * w2; acc[2][3] += a2 * w3;
            acc[3][0] += a3 * w0; acc[3][1] += a3 * w1; acc[3][2] += a3 * w2; acc[3][3] += a3 * w3;
        }
        #pragma unroll
        for (int i = 0; i < 4; i++)
            #pragma unroll
            for (int j = 0; j < 4; j++)
                ppart[(size_t)(ks * 32 + rt4 + i) * 1000 + cc + j] = acc[i][j];
    }
}

// sum pred partials + bias, write predictions, compute entropy certainty
__global__ void cert_kernel(const float* __restrict__ ppart, const float* __restrict__ out_b,
                            float* __restrict__ d_out, int t_iter)
{
    int b = blockIdx.x, t = threadIdx.x;
    __shared__ float red[256];
    float pv[4];
    float mx = -1e30f;
    #pragma unroll
    for (int ii = 0; ii < 4; ++ii) {
        int c = t + ii * 256;
        float v = -1e30f;
        if (c < 1000) {
            v = out_b[c];
            for (int ks = 0; ks < 8; ++ks) v += ppart[(size_t)(ks * 32 + b) * 1000 + c];
            d_out[(size_t)b * NOUT * TT + (size_t)c * TT + t_iter] = v;
        }
        pv[ii] = v;
        mx = fmaxf(mx, v);
    }
    red[t] = mx; __syncthreads();
    for (int off = 128; off; off >>= 1) { if (t < off) red[t] = fmaxf(red[t], red[t + off]); __syncthreads(); }
    mx = red[0]; __syncthreads();
    float s1 = 0.f, s2 = 0.f;
    #pragma unroll
    for (int ii = 0; ii < 4; ++ii) {
        int c = t + ii * 256;
        if (c < 1000) { float xx = pv[ii] - mx; float e = expf(xx); s1 += e; s2 += e * xx; }
    }
    red[t] = s1; __syncthreads();
    for (int off = 128; off; off >>= 1) { if (t < off) red[t] += red[t + off]; __syncthreads(); }
    s1 = red[0]; __syncthreads();
    red[t] = s2; __syncthreads();
    for (int off = 128; off; off >>= 1) { if (t < off) red[t] += red[t + off]; __syncthreads(); }
    s2 = red[0];
    if (t == 0) {
        float ne = -(s2 / s1 - logf(s1)) * (1.f / logf(1000.f));
        size_t base = (size_t)BB * NOUT * TT + (size_t)b * 2 * TT + t_iter;
        d_out[base] = ne;
        d_out[base + TT] = 1.f - ne;
    }
}

// ---------------------------------------------------------------------------
extern "C" void kernel_launch(void* const* d_in, const int* in_sizes, int n_in,
                              void* d_out, int out_size, void* d_ws, size_t ws_size,
                              hipStream_t stream)
{
    const float* x        = (const float*)d_in[0];
    const float* kv_w     = (const float*)d_in[1];
    const float* kv_b     = (const float*)d_in[2];
    const float* ln_kv_g  = (const float*)d_in[3];
    const float* ln_kv_b  = (const float*)d_in[4];
    const float* q_w      = (const float*)d_in[5];
    const float* q_b      = (const float*)d_in[6];
    const float* Wq       = (const float*)d_in[7];
    const float* bq       = (const float*)d_in[8];
    const float* Wk       = (const float*)d_in[9];
    const float* bk       = (const float*)d_in[10];
    const float* Wv       = (const float*)d_in[11];
    const float* bv       = (const float*)d_in[12];
    const float* Wo       = (const float*)d_in[13];
    const float* bo       = (const float*)d_in[14];
    const float* syn_w    = (const float*)d_in[15];
    const float* syn_b    = (const float*)d_in[16];
    const float* ln_syn_g = (const float*)d_in[17];
    const float* ln_syn_b = (const float*)d_in[18];
    const float* nlm_w1   = (const float*)d_in[19];
    const float* nlm_b1   = (const float*)d_in[20];
    const float* nlm_w2   = (const float*)d_in[21];
    const float* nlm_b2   = (const float*)d_in[22];
    const float* out_w    = (const float*)d_in[23];
    const float* out_b    = (const float*)d_in[24];
    const float* dec_a    = (const float*)d_in[25];
    const float* dec_o    = (const float*)d_in[26];
    const float* start_tr = (const float*)d_in[27];
    const float* start_ac = (const float*)d_in[28];
    const int*   idx_la   = (const int*)d_in[29];
    const int*   idx_ra   = (const int*)d_in[30];
    const int*   idx_lo   = (const int*)d_in[31];
    const int*   idx_ro   = (const int*)d_in[32];
    float* out = (float*)d_out;

    // workspace carve (floats)
    float* w = (float*)d_ws;
    float* kvbuf = w;            w += (size_t)8192 * 512;     // 4.19M
    float* khT   = w;            w += (size_t)8192 * 512;
    float* vhb   = w;            w += (size_t)8192 * 512;
    float* Wqq   = w;            w += (size_t)512 * 512;
    float* bqq   = w;            w += 512;
    float* W2    = w;            w += (size_t)512 * 4096;
    float* bias2 = w;            w += 4096;
    float* r_a   = w;            w += 512;
    float* r_o   = w;            w += 512;
    float* a_a   = w;            w += BB * NSA;
    float* b_a   = w;            w += BB * NSA;
    float* sync_a= w;            w += BB * NSA;
    float* a_o   = w;            w += BB * NSO;
    float* b_o   = w;            w += BB * NSO;
    float* sync_o= w;            w += BB * NSO;
    float* act   = w;            w += BB * DD;
    float* trace = w;            w += (size_t)BB * MM * DD;   // 1.64M
    float* qhb   = w;            w += BB * DIN;
    float* obuf  = w;            w += BB * DIN;
    float* upart = w;            w += (size_t)16 * 32 * 4096; // 2.1M
    float* ppart = w;            w += (size_t)8 * 32 * 1000;

    // ---- precompute ----
    init_kernel<<<6400, 256, 0, stream>>>(dec_a, dec_o, start_ac, start_tr, idx_lo, idx_ro,
                                          r_a, r_o, a_a, b_a, a_o, b_o, act, trace);
    gemm64<1, 0><<<dim3(128, 8), 256, 0, stream>>>(x, kv_w, kv_b, kvbuf, 8192, 512, 512);
    ln_rows<<<8192, 256, 0, stream>>>(kvbuf, ln_kv_g, ln_kv_b);
    gemm64<0, 1><<<dim3(128, 8), 256, 0, stream>>>(kvbuf, Wk, bk, khT, 8192, 512, 512);
    gemm64<0, 2><<<dim3(128, 8), 256, 0, stream>>>(kvbuf, Wv, bv, vhb, 8192, 512, 512);
    gemm64<0, 0><<<dim3(8, 8), 256, 0, stream>>>(q_w, Wq, nullptr, Wqq, 512, 512, 512);
    bqq_kernel<<<2, 256, 0, stream>>>(q_b, Wq, bq, bqq);
    gemm64<0, 0><<<dim3(8, 64), 256, 0, stream>>>(Wo, syn_w, nullptr, W2, 512, 4096, 512);
    bias2_kernel<<<16, 256, 0, stream>>>(bo, syn_w, syn_b, bias2);

    float* out_sync = out + (size_t)BB * NOUT * TT + (size_t)BB * 2 * TT;

    // ---- recurrent ticks ----
    for (int t = 0; t < TT; ++t) {
        sync_a_kernel<<<64, 256, 0, stream>>>(act, idx_la, idx_ra, r_a, a_a, b_a, sync_a);
        qh_kernel<<<64, 256, 0, stream>>>(sync_a, Wqq, bqq, qhb);
        attn_kernel<<<256, 256, 0, stream>>>(qhb, khT, vhb, obuf);
        syn_gemm<<<dim3(32, 16), 256, 0, stream>>>(obuf, act, W2, syn_w, upart);
        glu_ln_kernel<<<32, 256, 0, stream>>>(upart, bias2, ln_syn_g, ln_syn_b, trace, t);
        nlm_kernel<<<256, 256, 0, stream>>>(trace, nlm_w1, nlm_b1, nlm_w2, nlm_b2, act, t);
        sync_o_kernel<<<64, 256, 0, stream>>>(act, idx_lo, idx_ro, r_o, a_o, b_o, sync_o, out_sync, t);
        pred_gemm<<<dim3(8, 8), 256, 0, stream>>>(sync_o, out_w, ppart);
        cert_kernel<<<32, 256, 0, stream>>>(ppart, out_b, out, t);
    }
}